// Round 4
// baseline (158.912 us; speedup 1.0000x reference)
//
#include <hip/hip_runtime.h>

#define N_NODES 50000
#define N_EDGES 100000
#define NUM_RELS 200
#define DIM 64
#define CAP 512
#define TILES 8        // CAP/64 entries per tile
#define COLS 16        // cols per wave (4 waves = 64 cols)

// ---- workspace layout (int32 elements) ----
#define OFF_LAST 0
#define OFF_CUR  50000
#define OFF_BN   50200
#define OFF_BS   (50200 + NUM_RELS * CAP)

__global__ void init_kernel(int* __restrict__ ws) {
    int i = blockIdx.x * 256 + threadIdx.x;
    if (i < N_NODES) ws[OFF_LAST + i] = -1;
    if (i < NUM_RELS) ws[OFF_CUR + i] = 0;
}

__global__ void edge_max_kernel(const int* __restrict__ edges, int* __restrict__ ws) {
    int e = blockIdx.x * 256 + threadIdx.x;
    if (e < N_EDGES) atomicMax(&ws[OFF_LAST + edges[e * 3 + 2]], e);
}

__global__ void bucket_kernel(const int* __restrict__ edges, int* __restrict__ ws) {
    int n = blockIdx.x * 256 + threadIdx.x;
    if (n >= N_NODES) return;
    int li = ws[OFF_LAST + n];
    if (li < 0) return;
    int r = edges[li * 3 + 1];
    int s = edges[li * 3 + 0];
    int pos = atomicAdd(&ws[OFF_CUR + r], 1);
    if (pos < CAP) {
        ws[OFF_BN + r * CAP + pos] = n;
        ws[OFF_BS + r * CAP + pos] = s;
    }
}

// acc[COLS] += h-chunk (8 per-lane floats) x W rows (wave-uniform -> s_load)
__device__ __forceinline__ void body8c(float acc[COLS], const float* __restrict__ Wr,
                                       float4 a, float4 b) {
    float hv[8] = {a.x, a.y, a.z, a.w, b.x, b.y, b.z, b.w};
#pragma unroll
    for (int i = 0; i < 8; ++i) {
#pragma unroll
        for (int o = 0; o < COLS; ++o)
            acc[o] = fmaf(hv[i], Wr[i * DIM + o], acc[o]);
    }
}

// out = h @ wself. Block = 64 nodes x 4 waves; wave w -> cols [16w,16w+16).
__global__ __launch_bounds__(256) void self_kernel(const float* __restrict__ h,
                                                   const float* __restrict__ wself,
                                                   float* __restrict__ out) {
    int lane = threadIdx.x & 63;
    int w    = threadIdx.x >> 6;
    int n = blockIdx.x * 64 + lane;
    bool valid = n < N_NODES;
    int nc = valid ? n : (N_NODES - 1);
    const float* hp = h + (size_t)nc * DIM;
    const float* Wc = wself + w * COLS;

    float acc[COLS];
#pragma unroll
    for (int o = 0; o < COLS; ++o) acc[o] = 0.f;

#pragma unroll
    for (int ib = 0; ib < DIM; ib += 8) {
        float4 a = *(const float4*)(hp + ib);
        float4 b = *(const float4*)(hp + ib + 4);
        body8c(acc, Wc + ib * DIM, a, b);
    }

    if (valid) {
        float* op = out + (size_t)n * DIM + w * COLS;
#pragma unroll
        for (int o = 0; o < COLS; o += 4)
            *(float4*)(op + o) = make_float4(acc[o], acc[o+1], acc[o+2], acc[o+3]);
    }
}

// out[n] += h[src] @ weight[rel].  Block = (rel, 64-entry tile) x 4 col-waves.
__global__ __launch_bounds__(256) void msg_kernel(const float* __restrict__ h,
                                                  const float* __restrict__ weight,
                                                  const int* __restrict__ ws,
                                                  float* __restrict__ out) {
    int rel  = blockIdx.x >> 3;
    int tile = blockIdx.x & 7;
    int c = ws[OFF_CUR + rel];
    if (c > CAP) c = CAP;
    int start = tile * 64;
    if (start >= c) return;

    int lane = threadIdx.x & 63;
    int w    = threadIdx.x >> 6;
    int pos = start + lane;
    bool valid = pos < c;
    int cp = valid ? pos : (c - 1);
    int n = ws[OFF_BN + rel * CAP + cp];
    int s = ws[OFF_BS + rel * CAP + cp];
    const float* hp = h + (size_t)s * DIM;
    const float* Wc = weight + (size_t)rel * DIM * DIM + w * COLS;

    float acc[COLS];
#pragma unroll
    for (int o = 0; o < COLS; ++o) acc[o] = 0.f;

#pragma unroll
    for (int ib = 0; ib < DIM; ib += 8) {
        float4 a = *(const float4*)(hp + ib);
        float4 b = *(const float4*)(hp + ib + 4);
        body8c(acc, Wc + ib * DIM, a, b);
    }

    if (valid) {
        float* op = out + (size_t)n * DIM + w * COLS;
#pragma unroll
        for (int o = 0; o < COLS; o += 4) {
            float4 cur = *(const float4*)(op + o);
            *(float4*)(op + o) = make_float4(cur.x + acc[o], cur.y + acc[o+1],
                                             cur.z + acc[o+2], cur.w + acc[o+3]);
        }
    }
}

extern "C" void kernel_launch(void* const* d_in, const int* in_sizes, int n_in,
                              void* d_out, int out_size, void* d_ws, size_t ws_size,
                              hipStream_t stream) {
    const float* h      = (const float*)d_in[0];
    const int*   edges  = (const int*)d_in[1];
    const float* weight = (const float*)d_in[2];
    const float* wself  = (const float*)d_in[3];
    float* out = (float*)d_out;
    int* ws = (int*)d_ws;

    init_kernel<<<(N_NODES + 255) / 256, 256, 0, stream>>>(ws);
    edge_max_kernel<<<(N_EDGES + 255) / 256, 256, 0, stream>>>(edges, ws);
    bucket_kernel<<<(N_NODES + 255) / 256, 256, 0, stream>>>(edges, ws);
    self_kernel<<<(N_NODES + 63) / 64, 256, 0, stream>>>(h, wself, out);
    msg_kernel<<<NUM_RELS * TILES, 256, 0, stream>>>(h, weight, ws, out);
}

// Round 5
// 87.895 us; speedup vs baseline: 1.8080x; 1.8080x over previous
//
#include <hip/hip_runtime.h>

#define N_NODES 50000
#define N_EDGES 100000
#define NUM_RELS 200
#define DIM 64
#define CAP 512
#define TILES 8        // CAP/64 entries per tile
#define COLS 16        // cols per wave (4 waves = 64 cols)

// ---- workspace layout (int32 elements) ----
#define OFF_LAST 0
#define OFF_CUR  50000
#define OFF_BN   50200
#define OFF_BS   (50200 + NUM_RELS * CAP)

__global__ void init_kernel(int* __restrict__ ws) {
    int i = blockIdx.x * 256 + threadIdx.x;
    if (i < N_NODES) ws[OFF_LAST + i] = -1;
    if (i < NUM_RELS) ws[OFF_CUR + i] = 0;
}

__global__ void edge_max_kernel(const int* __restrict__ edges, int* __restrict__ ws) {
    int e = blockIdx.x * 256 + threadIdx.x;
    if (e < N_EDGES) atomicMax(&ws[OFF_LAST + edges[e * 3 + 2]], e);
}

__global__ void bucket_kernel(const int* __restrict__ edges, int* __restrict__ ws) {
    int n = blockIdx.x * 256 + threadIdx.x;
    if (n >= N_NODES) return;
    int li = ws[OFF_LAST + n];
    if (li < 0) return;
    int r = edges[li * 3 + 1];
    int s = edges[li * 3 + 0];
    int pos = atomicAdd(&ws[OFF_CUR + r], 1);
    if (pos < CAP) {
        ws[OFF_BN + r * CAP + pos] = n;
        ws[OFF_BS + r * CAP + pos] = s;
    }
}

// acc[COLS] += h-chunk (8 per-lane floats) x W rows (wave-uniform -> s_load)
__device__ __forceinline__ void body8c(float acc[COLS], const float* __restrict__ Wr,
                                       float4 a, float4 b) {
    float hv[8] = {a.x, a.y, a.z, a.w, b.x, b.y, b.z, b.w};
#pragma unroll
    for (int i = 0; i < 8; ++i) {
#pragma unroll
        for (int o = 0; o < COLS; ++o)
            acc[o] = fmaf(hv[i], Wr[i * DIM + o], acc[o]);
    }
}

// out = h @ wself. Block = 64 nodes x 4 waves; wave w -> cols [16w,16w+16).
__global__ __launch_bounds__(256) void self_kernel(const float* __restrict__ h,
                                                   const float* __restrict__ wself,
                                                   float* __restrict__ out) {
    int lane = threadIdx.x & 63;
    // readfirstlane -> SGPR -> W pointer is provably uniform -> s_load path
    int w = __builtin_amdgcn_readfirstlane(threadIdx.x >> 6);
    int n = blockIdx.x * 64 + lane;
    bool valid = n < N_NODES;
    int nc = valid ? n : (N_NODES - 1);
    const float* hp = h + (size_t)nc * DIM;
    const float* Wc = wself + w * COLS;

    float acc[COLS];
#pragma unroll
    for (int o = 0; o < COLS; ++o) acc[o] = 0.f;

#pragma unroll
    for (int ib = 0; ib < DIM; ib += 8) {
        float4 a = *(const float4*)(hp + ib);
        float4 b = *(const float4*)(hp + ib + 4);
        body8c(acc, Wc + ib * DIM, a, b);
    }

    if (valid) {
        float* op = out + (size_t)n * DIM + w * COLS;
#pragma unroll
        for (int o = 0; o < COLS; o += 4)
            *(float4*)(op + o) = make_float4(acc[o], acc[o+1], acc[o+2], acc[o+3]);
    }
}

// out[n] += h[src] @ weight[rel].  Block = (rel, 64-entry tile) x 4 col-waves.
__global__ __launch_bounds__(256) void msg_kernel(const float* __restrict__ h,
                                                  const float* __restrict__ weight,
                                                  const int* __restrict__ ws,
                                                  float* __restrict__ out) {
    int rel  = blockIdx.x >> 3;
    int tile = blockIdx.x & 7;
    int c = ws[OFF_CUR + rel];
    if (c > CAP) c = CAP;
    int start = tile * 64;
    if (start >= c) return;

    int lane = threadIdx.x & 63;
    int w = __builtin_amdgcn_readfirstlane(threadIdx.x >> 6);
    int pos = start + lane;
    bool valid = pos < c;
    int cp = valid ? pos : (c - 1);
    int n = ws[OFF_BN + rel * CAP + cp];
    int s = ws[OFF_BS + rel * CAP + cp];
    const float* hp = h + (size_t)s * DIM;
    const float* Wc = weight + (size_t)rel * DIM * DIM + w * COLS;

    float acc[COLS];
#pragma unroll
    for (int o = 0; o < COLS; ++o) acc[o] = 0.f;

#pragma unroll
    for (int ib = 0; ib < DIM; ib += 8) {
        float4 a = *(const float4*)(hp + ib);
        float4 b = *(const float4*)(hp + ib + 4);
        body8c(acc, Wc + ib * DIM, a, b);
    }

    if (valid) {
        float* op = out + (size_t)n * DIM + w * COLS;
#pragma unroll
        for (int o = 0; o < COLS; o += 4) {
            float4 cur = *(const float4*)(op + o);
            *(float4*)(op + o) = make_float4(cur.x + acc[o], cur.y + acc[o+1],
                                             cur.z + acc[o+2], cur.w + acc[o+3]);
        }
    }
}

extern "C" void kernel_launch(void* const* d_in, const int* in_sizes, int n_in,
                              void* d_out, int out_size, void* d_ws, size_t ws_size,
                              hipStream_t stream) {
    const float* h      = (const float*)d_in[0];
    const int*   edges  = (const int*)d_in[1];
    const float* weight = (const float*)d_in[2];
    const float* wself  = (const float*)d_in[3];
    float* out = (float*)d_out;
    int* ws = (int*)d_ws;

    init_kernel<<<(N_NODES + 255) / 256, 256, 0, stream>>>(ws);
    edge_max_kernel<<<(N_EDGES + 255) / 256, 256, 0, stream>>>(edges, ws);
    bucket_kernel<<<(N_NODES + 255) / 256, 256, 0, stream>>>(edges, ws);
    self_kernel<<<(N_NODES + 63) / 64, 256, 0, stream>>>(h, wself, out);
    msg_kernel<<<NUM_RELS * TILES, 256, 0, stream>>>(h, weight, ws, out);
}